// Round 8
// baseline (327.902 us; speedup 1.0000x reference)
//
#include <hip/hip_runtime.h>
#include <hip/hip_bf16.h>

#define BATCH 8
#define CIN   128
#define HH    256
#define WW    256
#define OUTC  64
#define INCH  1152   // CIN*9
#define HW    (HH*WW)

#define XT_BYTES   ((size_t)BATCH * HH * WW * CIN * 2)          // 134217728
#define WMOD_BYTES ((size_t)BATCH * 9 * OUTC * CIN * 2)         // 1179648
#define ZG_BYTES   16

typedef __attribute__((ext_vector_type(8))) short short8;
typedef __attribute__((ext_vector_type(4))) float f32x4;
typedef __attribute__((ext_vector_type(4))) unsigned int u32x4;

__device__ __forceinline__ unsigned short bf16r(float f) {
    unsigned u = __builtin_bit_cast(unsigned, f);
    u += 0x7fffu + ((u >> 16) & 1u);
    return (unsigned short)(u >> 16);
}

__device__ __forceinline__ void gload_lds16(const unsigned short* src,
                                            unsigned short* dst_lds) {
    __builtin_amdgcn_global_load_lds(
        (const __attribute__((address_space(1))) unsigned int*)(const void*)src,
        (__attribute__((address_space(3))) unsigned int*)(void*)dst_lds,
        16, 0, 0);
}

// wmod[b][tap][o][c] = bf16(weight[o][c*9+tap] * style[b][c*9+tap])
__global__ void __launch_bounds__(256) wmod_kernel(const float* __restrict__ weight,
                                                   const float* __restrict__ style,
                                                   unsigned short* __restrict__ wmod) {
    int i = blockIdx.x * 256 + threadIdx.x;
    if (i >= BATCH * 9 * OUTC * CIN) return;
    int c    = i & (CIN - 1);
    int rest = i >> 7;
    int o    = rest & (OUTC - 1);
    int bt   = rest >> 6;          // b*9 + tap
    int tap  = bt % 9;
    int b    = bt / 9;
    int k    = c * 9 + tap;
    float v = weight[o * INCH + k] * style[b * INCH + k];
    wmod[i] = bf16r(v);
}

// xT[b][h][w][c] = bf16(x[b][c][h][w]).  Block: (wt, h, b); 256 threads.
// Lane = w (coalesced 256B reads per c-row); thread owns 32 channels,
// writes 4x16B = one full 64B sector.
__global__ void __launch_bounds__(256) transpose_kernel(const float* __restrict__ x,
                                                        unsigned short* __restrict__ xT) {
    const int w  = blockIdx.x * 64 + (threadIdx.x & 63);
    const int c0 = (threadIdx.x >> 6) * 32;
    const int h  = blockIdx.y;
    const int b  = blockIdx.z;

    const float* xp = x + ((size_t)(b * CIN + c0)) * HW + h * WW + w;
    unsigned short* op = xT + ((size_t)(b * HH + h) * WW + w) * CIN + c0;

    float f[32];
#pragma unroll
    for (int j = 0; j < 32; ++j) f[j] = xp[(size_t)j * HW];

    unsigned pk[16];
#pragma unroll
    for (int j = 0; j < 16; ++j)
        pk[j] = (unsigned)bf16r(f[2 * j]) | ((unsigned)bf16r(f[2 * j + 1]) << 16);

#pragma unroll
    for (int u = 0; u < 4; ++u) {
        u32x4 v = {pk[u * 4 + 0], pk[u * 4 + 1], pk[u * 4 + 2], pk[u * 4 + 3]};
        *(u32x4*)(op + u * 8) = v;
    }
}

// ---------------- main conv, xT + global_load_lds path ----------------
// Block: 512 threads = 8 waves; tile 64o x (8h x 32w) px; wave 32o x 64px.
// LDS (double-buffered): paired pixel-rows, 128B/q-row, granule (q,g):
//   g = (((s&1)<<2)|cg) ^ (q&7), q = s>>1   [s = halo pixel, cg = c-group]
// Staged by global_load_lds with LINEAR dest granule G (q=G>>3, g=G&7) and
// per-lane SOURCE = inverse-swizzled xT granule (16B contiguous; OOB->zerog).
// stage(k+1) issued before compute(k): vmcnt drain at the barrier lands a
// full compute phase later -> pipelined with zero staging VGPRs.
__global__ void __launch_bounds__(512, 4) conv2_kernel(
    const unsigned short* __restrict__ xT,
    const unsigned short* __restrict__ wmod,
    const unsigned short* __restrict__ zerog,
    float* __restrict__ out)
{
    __shared__ __align__(16) unsigned short xs_sm[2][170 * 64];

    const int tid = threadIdx.x;           // 0..511
    const int bx  = blockIdx.x;            // 0..255 spatial tile
    const int b   = blockIdx.y;            // batch
    const int h0  = (bx >> 3) * 8;
    const int w0  = (bx & 7) * 32;

    const int wv  = tid >> 6;              // 0..7
    const int wr  = wv >> 2;               // o-half
    const int wc  = wv & 3;                // px-quarter
    const int l15 = tid & 15;
    const int kg  = (tid >> 4) & 3;

    // ---- staging source geometry: granule G = tid + i*512 (G < 1360)
    size_t goff[3];
    bool   gok[3];
#pragma unroll
    for (int i = 0; i < 3; ++i) {
        int G = tid + i * 512;
        int Gc = (G < 1360) ? G : 0;
        int q = Gc >> 3, g = Gc & 7;
        int pc = g ^ (q & 7);
        int s  = (q << 1) | (pc >> 2);
        int cg = pc & 3;
        int r   = s / 34;
        int col = s - r * 34;
        int h = h0 - 1 + r, w = w0 - 1 + col;
        gok[i]  = ((unsigned)h < HH) && ((unsigned)w < WW);
        goff[i] = ((size_t)(b * HH + (h & 255)) * WW + (w & 255)) * CIN + cg * 8;
    }

    int sbase[4];
#pragma unroll
    for (int ni = 0; ni < 4; ++ni) {
        int p = wc * 64 + ni * 16 + l15;
        sbase[ni] = (p >> 5) * 34 + (p & 31);
    }

    f32x4 acc[2][4];
#pragma unroll
    for (int mi = 0; mi < 2; ++mi)
#pragma unroll
        for (int ni = 0; ni < 4; ++ni) acc[mi][ni] = (f32x4){0.f, 0.f, 0.f, 0.f};

    auto stage = [&](int chunk, unsigned short* buf) {
#pragma unroll
        for (int i = 0; i < 3; ++i) {
            if (i < 2 || tid < 336) {
                const unsigned short* src =
                    gok[i] ? (xT + goff[i] + chunk * 32) : zerog;
                unsigned short* dst = buf + (i * 512 + wv * 64) * 8;
                gload_lds16(src, dst);
            }
        }
    };

    auto compute = [&](int chunk, const unsigned short* xs) {
        const unsigned short* wmb =
            wmod + ((size_t)(b * 9) * OUTC) * CIN + chunk * 32;
#pragma unroll
        for (int tap = 0; tap < 9; ++tap) {
            const int kh = tap / 3, kw = tap % 3;

            short8 A[2];
            const unsigned short* wt = wmb + (size_t)tap * OUTC * CIN;
#pragma unroll
            for (int mi = 0; mi < 2; ++mi)
                A[mi] = *(const short8*)(wt + (wr * 32 + mi * 16 + l15) * CIN +
                                         kg * 8);

            short8 Bv[4];
#pragma unroll
            for (int ni = 0; ni < 4; ++ni) {
                int s = sbase[ni] + kh * 34 + kw;
                int q = s >> 1;
                int g = (((s & 1) << 2) | kg) ^ (q & 7);
                Bv[ni] = *(const short8*)&xs[q * 64 + g * 8];
            }
#pragma unroll
            for (int mi = 0; mi < 2; ++mi)
#pragma unroll
                for (int ni = 0; ni < 4; ++ni)
                    acc[mi][ni] = __builtin_amdgcn_mfma_f32_16x16x32_bf16(
                        A[mi], Bv[ni], acc[mi][ni], 0, 0, 0);
        }
    };

    // ---- pipelined chunk loop (static buffer names)
    stage(0, xs_sm[0]);
    __syncthreads();                       // buf0 ready
    stage(1, xs_sm[1]);                    // in flight under compute(0)
    compute(0, xs_sm[0]);
    __syncthreads();                       // drains stage(1); buf0 free
    stage(2, xs_sm[0]);
    compute(1, xs_sm[1]);
    __syncthreads();
    stage(3, xs_sm[1]);
    compute(2, xs_sm[0]);
    __syncthreads();
    compute(3, xs_sm[1]);

    // ---- epilogue: D mapping col=lane&15 (pixel), row=(lane>>4)*4+r (o)
    float* op = out + ((size_t)b * OUTC) * HW;
#pragma unroll
    for (int mi = 0; mi < 2; ++mi) {
#pragma unroll
        for (int ni = 0; ni < 4; ++ni) {
            int p = wc * 64 + ni * 16 + l15;
            int h = h0 + (p >> 5), w = w0 + (p & 31);
#pragma unroll
            for (int r = 0; r < 4; ++r) {
                int o = wr * 32 + mi * 16 + kg * 4 + r;
                op[(size_t)o * HW + h * WW + w] = acc[mi][ni][r];
            }
        }
    }
}

// ---------------- fallback conv (round-7 path, fp32 staging) ----------------
template <bool GW>
__global__ void __launch_bounds__(512, 4) conv_kernel(
    const float* __restrict__ x,
    const unsigned short* __restrict__ wmod,
    const float* __restrict__ weight,
    const float* __restrict__ style,
    float* __restrict__ out)
{
    __shared__ __align__(16) unsigned short xs_sm[170 * 64];

    const int tid = threadIdx.x;
    const int bx  = blockIdx.x;
    const int b   = blockIdx.y;
    const int h0  = (bx >> 3) * 8;
    const int w0  = (bx & 7) * 32;

    const int wv  = tid >> 6;
    const int wr  = wv >> 2;
    const int wc  = wv & 3;
    const int l15 = tid & 15;
    const int kg  = (tid >> 4) & 3;

    int sbase[4];
#pragma unroll
    for (int ni = 0; ni < 4; ++ni) {
        int p = wc * 64 + ni * 16 + l15;
        sbase[ni] = (p >> 5) * 34 + (p & 31);
    }

    const bool tvalid = tid < 400;
    const int scg = tvalid ? tid / 100 : 0;
    const int srw = tvalid ? tid % 100 : 0;
    const int sr  = srw / 10;
    const int swq = srw % 10;
    const int sh  = h0 - 1 + sr;
    const bool hok = (unsigned)sh < HH;
    const int wload  = w0 - 4 + swq * 4;
    const int wclamp = min(max(wload, 0), WW - 4);
    const int gbase  = (hok ? sh : 0) * WW + wclamp;

    f32x4 acc[2][4];
#pragma unroll
    for (int mi = 0; mi < 2; ++mi)
#pragma unroll
        for (int ni = 0; ni < 4; ++ni) acc[mi][ni] = (f32x4){0.f, 0.f, 0.f, 0.f};

    for (int chunk = 0; chunk < 4; ++chunk) {
        if (chunk) __syncthreads();

        if (tvalid) {
            const float* xp =
                x + ((size_t)(b * CIN + chunk * 32 + scg * 8)) * HW + gbase;
            f32x4 f[8];
#pragma unroll
            for (int j = 0; j < 8; ++j)
                f[j] = hok ? *(const f32x4*)(xp + (size_t)j * HW)
                           : (f32x4){0.f, 0.f, 0.f, 0.f};
#pragma unroll
            for (int u = 0; u < 4; ++u) {
                int w   = wload + u;
                int col = w - (w0 - 1);
                if (col >= 0 && col <= 33) {
                    bool wok = hok && ((unsigned)w < WW);
                    short8 sv;
#pragma unroll
                    for (int j = 0; j < 8; ++j)
                        sv[j] = wok ? (short)bf16r(f[j][u]) : (short)0;
                    int s = sr * 34 + col;
                    int q = s >> 1;
                    int g = (((s & 1) << 2) | scg) ^ (q & 7);
                    *(short8*)&xs_sm[q * 64 + g * 8] = sv;
                }
            }
        }
        __syncthreads();

        const unsigned short* wmb = wmod + ((size_t)(b * 9) * OUTC) * CIN + chunk * 32;
#pragma unroll
        for (int tap = 0; tap < 9; ++tap) {
            const int kh = tap / 3, kw = tap % 3;

            short8 A[2];
            if (GW) {
                const unsigned short* wt = wmb + (size_t)tap * OUTC * CIN;
#pragma unroll
                for (int mi = 0; mi < 2; ++mi)
                    A[mi] = *(const short8*)(wt + (wr * 32 + mi * 16 + l15) * CIN +
                                             kg * 8);
            } else {
#pragma unroll
                for (int mi = 0; mi < 2; ++mi) {
                    int o = wr * 32 + mi * 16 + l15;
#pragma unroll
                    for (int j = 0; j < 8; ++j) {
                        int c = chunk * 32 + kg * 8 + j;
                        int k = c * 9 + tap;
                        A[mi][j] = (short)bf16r(weight[o * INCH + k] *
                                                style[b * INCH + k]);
                    }
                }
            }

            short8 Bv[4];
#pragma unroll
            for (int ni = 0; ni < 4; ++ni) {
                int s = sbase[ni] + kh * 34 + kw;
                int q = s >> 1;
                int g = (((s & 1) << 2) | kg) ^ (q & 7);
                Bv[ni] = *(const short8*)&xs_sm[q * 64 + g * 8];
            }
#pragma unroll
            for (int mi = 0; mi < 2; ++mi)
#pragma unroll
                for (int ni = 0; ni < 4; ++ni)
                    acc[mi][ni] = __builtin_amdgcn_mfma_f32_16x16x32_bf16(
                        A[mi], Bv[ni], acc[mi][ni], 0, 0, 0);
        }
    }

    float* op = out + ((size_t)b * OUTC) * HW;
#pragma unroll
    for (int mi = 0; mi < 2; ++mi) {
#pragma unroll
        for (int ni = 0; ni < 4; ++ni) {
            int p = wc * 64 + ni * 16 + l15;
            int h = h0 + (p >> 5), w = w0 + (p & 31);
#pragma unroll
            for (int r = 0; r < 4; ++r) {
                int o = wr * 32 + mi * 16 + kg * 4 + r;
                op[(size_t)o * HW + h * WW + w] = acc[mi][ni][r];
            }
        }
    }
}

extern "C" void kernel_launch(void* const* d_in, const int* in_sizes, int n_in,
                              void* d_out, int out_size, void* d_ws, size_t ws_size,
                              hipStream_t stream) {
    const float* x      = (const float*)d_in[0];
    const float* style  = (const float*)d_in[1];
    const float* weight = (const float*)d_in[2];
    float* out = (float*)d_out;

    const int wmod_total = BATCH * 9 * OUTC * CIN;

    if (ws_size >= XT_BYTES + WMOD_BYTES + ZG_BYTES) {
        unsigned short* xT    = (unsigned short*)d_ws;
        unsigned short* wmodp = (unsigned short*)((char*)d_ws + XT_BYTES);
        unsigned short* zerog = (unsigned short*)((char*)d_ws + XT_BYTES + WMOD_BYTES);

        wmod_kernel<<<(wmod_total + 255) / 256, 256, 0, stream>>>(weight, style, wmodp);
        transpose_kernel<<<dim3(4, HH, BATCH), 256, 0, stream>>>(x, xT);
        hipMemsetAsync(zerog, 0, ZG_BYTES, stream);
        conv2_kernel<<<dim3(256, BATCH), 512, 0, stream>>>(xT, wmodp, zerog, out);
    } else if (ws_size >= WMOD_BYTES) {
        unsigned short* wmodp = (unsigned short*)d_ws;
        wmod_kernel<<<(wmod_total + 255) / 256, 256, 0, stream>>>(weight, style, wmodp);
        conv_kernel<true><<<dim3(256, BATCH), 512, 0, stream>>>(
            x, wmodp, nullptr, nullptr, out);
    } else {
        conv_kernel<false><<<dim3(256, BATCH), 512, 0, stream>>>(
            x, nullptr, weight, style, out);
    }
}